// Round 2
// baseline (523.457 us; speedup 1.0000x reference)
//
#include <hip/hip_runtime.h>

static constexpr int NB   = 128;
static constexpr int NCIN = 64;
static constexpr int NG   = 8;
static constexpr int NH   = 14;
static constexpr int NP   = 16;
static constexpr int HH   = NH * NH;   // 196
static constexpr int LROW = 20;        // padded t4 row: l in [-2,17]

// ---------------------------------------------------------------------------
// Fused: channel-mix (64->16) -> 5-tap conv along l (+boundary corrections)
// -> roll -> transposed output. One block per (b, o); 256 threads.
//
// out[b, j*16+p, o, n] = sum_{g,d} t4[b,g,o_src,n+d-2,p] * W2[g,d,j]
//                        - [n==0]  wconv[g,0,2,j]*t4[l=0]
//                        - [n==13] wconv[g,2,0,j]*t4[l=13]
// with t4[b,g,m,l,p] = sum_cin x[b,cin,g,m,l]*wmix[cin,p], o_src=(o+13)%14,
// W2[g,d,j] = sum_{i+k==d} wconv[g,i,k,j].
// ---------------------------------------------------------------------------
__global__ __launch_bounds__(256, 4) void fused_kernel(const float* __restrict__ x,
                                                       const float* __restrict__ wconv,
                                                       const float* __restrict__ wmix,
                                                       float* __restrict__ out) {
    __shared__ __align__(16) float lds[512 * 15];   // 30720 B (epilogue overlay)
    float* t4s   = lds;          // [8][16][LROW] = 2560
    float* wmixs = lds + 2560;   // [64][16]      = 1024
    float* w2s   = lds + 3584;   // [8][5][32]    = 1280
    float* wcs   = lds + 4864;   // [2][8][32]    =  512  (total 5376 < 7680)

    const int tid   = threadIdx.x;
    const int b     = blockIdx.x / NH;
    const int o     = blockIdx.x % NH;
    const int o_src = (o + NH - 1) % NH;

    // ---- phase 0: weights to LDS + zero t4s pads ----
#pragma unroll
    for (int r = 0; r < 4; r++) {                  // wmix: 1024
        int idx = r * 256 + tid;
        wmixs[idx] = wmix[idx];
    }
#pragma unroll
    for (int r = 0; r < 5; r++) {                  // W2: 1280
        int idx = r * 256 + tid;
        int g   = idx / 160;
        int di  = (idx / 32) % 5;
        int j   = idx % 32;
        int ilo = di > 2 ? di - 2 : 0;
        int ihi = di < 2 ? di : 2;
        float s = 0.f;
        for (int i = ilo; i <= ihi; i++) s += wconv[((g * 3 + i) * 3 + (di - i)) * 32 + j];
        w2s[idx] = s;
    }
#pragma unroll
    for (int r = 0; r < 2; r++) {                  // corrections: 512
        int idx = r * 256 + tid;
        int sel = idx / 256;
        int g   = (idx / 32) % 8;
        int j   = idx % 32;
        wcs[idx] = wconv[(g * 9 + (sel ? 6 : 2)) * 32 + j];
    }
#pragma unroll
    for (int r = 0; r < 3; r++) {                  // zero pads: 128 gp * 6
        int idx = r * 256 + tid;
        int gp  = idx / 6;
        int s   = idx % 6;
        int l2  = (s < 2) ? s : (14 + s);
        t4s[gp * LROW + l2] = 0.f;
    }
    __syncthreads();

    // ---- phase 1: mix. thread = (g, pp, lq): lq=l-quad, pp=p-pair ----
    {
        const int lq = tid & 3;
        const int pp = (tid >> 2) & 7;
        const int g  = tid >> 5;

        float acc[2][4];
#pragma unroll
        for (int pi = 0; pi < 2; pi++)
#pragma unroll
            for (int li = 0; li < 4; li++) acc[pi][li] = 0.f;

        const float* xb = x + (size_t)b * (NCIN * NG * HH) + (size_t)g * HH
                            + o_src * NH + lq * 4;
        const bool full = (lq < 3);

#pragma unroll 4
        for (int cin = 0; cin < NCIN; cin++) {
            const float* xp = xb + (size_t)cin * (NG * HH);
            float2 va = *reinterpret_cast<const float2*>(xp);
            float2 vb = full ? *reinterpret_cast<const float2*>(xp + 2)
                             : make_float2(0.f, 0.f);
            float2 w = *reinterpret_cast<const float2*>(&wmixs[cin * NP + pp * 2]);
            acc[0][0] += va.x * w.x;  acc[0][1] += va.y * w.x;
            acc[0][2] += vb.x * w.x;  acc[0][3] += vb.y * w.x;
            acc[1][0] += va.x * w.y;  acc[1][1] += va.y * w.y;
            acc[1][2] += vb.x * w.y;  acc[1][3] += vb.y * w.y;
        }
        const int nl = full ? 4 : 2;
#pragma unroll
        for (int pi = 0; pi < 2; pi++)
            for (int li = 0; li < nl; li++)
                t4s[(g * NP + pp * 2 + pi) * LROW + 2 + lq * 4 + li] = acc[pi][li];
    }
    __syncthreads();

    // ---- phase 2: conv. thread = (p, jg, h); n = h*7 + nn ----
    const int p  = tid & 15;
    const int jg = (tid >> 4) & 7;
    const int h  = tid >> 7;

    float acc[7][4];
#pragma unroll
    for (int nn = 0; nn < 7; nn++) {
        acc[nn][0] = 0.f; acc[nn][1] = 0.f; acc[nn][2] = 0.f; acc[nn][3] = 0.f;
    }

    for (int g = 0; g < NG; g++) {
        // rowbuf holds t4s row floats [4h .. 4h+15]
        float rowbuf[16];
        const float* rp = &t4s[(g * NP + p) * LROW + 4 * h];
#pragma unroll
        for (int q = 0; q < 4; q++) {
            float4 v = *reinterpret_cast<const float4*>(rp + q * 4);
            rowbuf[q * 4 + 0] = v.x; rowbuf[q * 4 + 1] = v.y;
            rowbuf[q * 4 + 2] = v.z; rowbuf[q * 4 + 3] = v.w;
        }
#pragma unroll
        for (int di = 0; di < 5; di++) {
            float4 w = *reinterpret_cast<const float4*>(&w2s[(g * 5 + di) * 32 + jg * 4]);
#pragma unroll
            for (int nn = 0; nn < 7; nn++) {
                float rv = rowbuf[3 * h + nn + di];
                acc[nn][0] += rv * w.x;
                acc[nn][1] += rv * w.y;
                acc[nn][2] += rv * w.z;
                acc[nn][3] += rv * w.w;
            }
        }
        if (h == 0) {        // n==0 correction: t4 l=0 -> float idx 2
            float4 c0 = *reinterpret_cast<const float4*>(&wcs[g * 32 + jg * 4]);
            float r0 = rowbuf[2];
            acc[0][0] -= r0 * c0.x; acc[0][1] -= r0 * c0.y;
            acc[0][2] -= r0 * c0.z; acc[0][3] -= r0 * c0.w;
        } else {             // n==13 correction: t4 l=13 -> float idx 15 -> buf 11
            float4 c1 = *reinterpret_cast<const float4*>(&wcs[256 + g * 32 + jg * 4]);
            float r13 = rowbuf[11];
            acc[6][0] -= r13 * c1.x; acc[6][1] -= r13 * c1.y;
            acc[6][2] -= r13 * c1.z; acc[6][3] -= r13 * c1.w;
        }
    }
    __syncthreads();   // weights/t4s dead; overlay lds as output stage

    // ---- phase 3: stage to LDS (stride 15 -> conflict-light) ----
#pragma unroll
    for (int jj = 0; jj < 4; jj++) {
        int c = (jg * 4 + jj) * NP + p;
#pragma unroll
        for (int nn = 0; nn < 7; nn++) lds[c * 15 + h * 7 + nn] = acc[nn][jj];
    }
    __syncthreads();

    // ---- phase 4: coalesced-ish global write (56 B runs per channel) ----
    float* ob = out + (size_t)b * 512 * HH + (size_t)o * NH;
#pragma unroll
    for (int r = 0; r < 28; r++) {                 // 7168 = 512*14
        int idx = r * 256 + tid;
        int c   = idx / 14;
        int n   = idx % 14;
        ob[(size_t)c * HH + n] = lds[c * 15 + n];
    }
}

extern "C" void kernel_launch(void* const* d_in, const int* in_sizes, int n_in,
                              void* d_out, int out_size, void* d_ws, size_t ws_size,
                              hipStream_t stream) {
    const float* x     = (const float*)d_in[0];
    const float* wconv = (const float*)d_in[1];
    const float* wmix  = (const float*)d_in[2];
    float* out = (float*)d_out;

    fused_kernel<<<NB * NH, 256, 0, stream>>>(x, wconv, wmix, out);
}